// Round 1
// baseline (2165.753 us; speedup 1.0000x reference)
//
#include <hip/hip_runtime.h>
#include <hip/hip_bf16.h>

#define NN 50000
#define NE 800000
#define DD 96

// ---------------------------------------------------------------------------
// Kernel 1: Vp = relu(leaky_relu(V) @ A_w + A_b)
// block = 256 threads, tile = 32 rows x 96 cols, thread = 2 rows x 6 cols
// ---------------------------------------------------------------------------
__global__ __launch_bounds__(256) void k_vp(
    const float* __restrict__ V, const float* __restrict__ Aw,
    const float* __restrict__ Ab, float* __restrict__ Vp)
{
    __shared__ float sW[DD * DD];   // 36864 B
    __shared__ float sV[32 * DD];   // 12288 B
    __shared__ float sB[DD];

    const int tid = threadIdx.x;

    for (int i = tid; i < DD * DD / 4; i += 256)
        reinterpret_cast<float4*>(sW)[i] = reinterpret_cast<const float4*>(Aw)[i];
    if (tid < DD / 4)
        reinterpret_cast<float4*>(sB)[tid] = reinterpret_cast<const float4*>(Ab)[tid];

    const int row0 = blockIdx.x * 32;
    const int nr = min(32, NN - row0);
    for (int i = tid; i < nr * DD / 4; i += 256) {
        float4 v = reinterpret_cast<const float4*>(V + (size_t)row0 * DD)[i];
        v.x = v.x > 0.f ? v.x : 0.2f * v.x;
        v.y = v.y > 0.f ? v.y : 0.2f * v.y;
        v.z = v.z > 0.f ? v.z : 0.2f * v.z;
        v.w = v.w > 0.f ? v.w : 0.2f * v.w;
        reinterpret_cast<float4*>(sV)[i] = v;
    }
    __syncthreads();

    const int cg = tid & 15;        // 16 col groups of 6
    const int rg = tid >> 4;        // 16 row groups of 2
    const int c0 = cg * 6;
    const int r0 = rg * 2;

    float acc0[6], acc1[6];
#pragma unroll
    for (int j = 0; j < 6; ++j) { acc0[j] = sB[c0 + j]; acc1[j] = sB[c0 + j]; }

#pragma unroll 8
    for (int k = 0; k < DD; ++k) {
        const float v0 = sV[r0 * DD + k];
        const float v1 = sV[(r0 + 1) * DD + k];
#pragma unroll
        for (int j = 0; j < 6; ++j) {
            const float w = sW[k * DD + c0 + j];
            acc0[j] = fmaf(v0, w, acc0[j]);
            acc1[j] = fmaf(v1, w, acc1[j]);
        }
    }

    const int rowA = row0 + r0;
    if (rowA < NN) {
#pragma unroll
        for (int j = 0; j < 6; ++j)
            Vp[(size_t)rowA * DD + c0 + j] = fmaxf(acc0[j], 0.f);
    }
    if (rowA + 1 < NN) {
#pragma unroll
        for (int j = 0; j < 6; ++j)
            Vp[(size_t)(rowA + 1) * DD + c0 + j] = fmaxf(acc1[j], 0.f);
    }
}

// ---------------------------------------------------------------------------
// Kernel 2: per edge e with weight w = edge_attr[e][1]:
//   aggV[dst] += w * Vp[src]   (96 floats)
//   G[dst]    += w * E[e]      (96 floats)
//   ssum[dst] += w
// 24 threads per edge, one float4 of each stream per thread.
// ---------------------------------------------------------------------------
__global__ __launch_bounds__(256) void k_edge(
    const float* __restrict__ Vp, const float* __restrict__ E,
    const float* __restrict__ ea, const int* __restrict__ src,
    const int* __restrict__ dst, float* __restrict__ aggV,
    float* __restrict__ G, float* __restrict__ ssum)
{
    const int g = blockIdx.x * 256 + threadIdx.x;
    const int e = g / 24;
    if (e >= NE) return;
    const int lane = g - e * 24;

    const float w = ea[(size_t)e * 4 + 1];
    const int s = src[e];
    const int d = dst[e];

    const float4 Ev = reinterpret_cast<const float4*>(E + (size_t)e * DD)[lane];
    const float4 Vv = reinterpret_cast<const float4*>(Vp + (size_t)s * DD)[lane];

    float* gp = G + (size_t)d * DD + lane * 4;
    float* ap = aggV + (size_t)d * DD + lane * 4;

    atomicAdd(gp + 0, w * Ev.x);
    atomicAdd(gp + 1, w * Ev.y);
    atomicAdd(gp + 2, w * Ev.z);
    atomicAdd(gp + 3, w * Ev.w);
    atomicAdd(ap + 0, w * Vv.x);
    atomicAdd(ap + 1, w * Vv.y);
    atomicAdd(ap + 2, w * Vv.z);
    atomicAdd(ap + 3, w * Vv.w);
    if (lane == 0) atomicAdd(&ssum[d], w);
}

// ---------------------------------------------------------------------------
// Kernel 3: fused finalize.
//   a1  = aggV + G @ M_w + ssum * M_b          (no relu)
//   out = relu(a1 @ W1 + V_in @ W2 + W_b)      (W_w = [W1; W2], 192x96)
// 3 phases with sequential LDS weight reloads. LDS = 61.8 KB.
// ---------------------------------------------------------------------------
__global__ __launch_bounds__(256) void k_out(
    const float* __restrict__ aggV, const float* __restrict__ G,
    const float* __restrict__ ssum, const float* __restrict__ Vin,
    const float* __restrict__ Mw, const float* __restrict__ Mb,
    const float* __restrict__ Ww, const float* __restrict__ Wb,
    float* __restrict__ out)
{
    __shared__ float sW[DD * DD];   // 36864 B  (Mw, then W1, then W2)
    __shared__ float sX[32 * DD];   // 12288 B  (G tile, then V_in tile)
    __shared__ float sA[32 * DD];   // 12288 B  (a1 tile)
    __shared__ float sB[DD];        // bias (Mb, then Wb)

    const int tid = threadIdx.x;
    const int row0 = blockIdx.x * 32;
    const int nr = min(32, NN - row0);
    const int cg = tid & 15;
    const int rg = tid >> 4;
    const int c0 = cg * 6;
    const int r0 = rg * 2;
    const int rowA = row0 + r0;
    const int rowB = rowA + 1;

    // ---- phase 1: a1 = aggV + G @ Mw + ssum * Mb
    for (int i = tid; i < DD * DD / 4; i += 256)
        reinterpret_cast<float4*>(sW)[i] = reinterpret_cast<const float4*>(Mw)[i];
    for (int i = tid; i < nr * DD / 4; i += 256)
        reinterpret_cast<float4*>(sX)[i] =
            reinterpret_cast<const float4*>(G + (size_t)row0 * DD)[i];
    if (tid < DD / 4)
        reinterpret_cast<float4*>(sB)[tid] = reinterpret_cast<const float4*>(Mb)[tid];
    __syncthreads();

    float a0[6], a1[6];
    {
        const float s0 = (rowA < NN) ? ssum[rowA] : 0.f;
        const float s1 = (rowB < NN) ? ssum[rowB] : 0.f;
#pragma unroll
        for (int j = 0; j < 6; ++j) {
            a0[j] = (rowA < NN) ? aggV[(size_t)rowA * DD + c0 + j] + s0 * sB[c0 + j] : 0.f;
            a1[j] = (rowB < NN) ? aggV[(size_t)rowB * DD + c0 + j] + s1 * sB[c0 + j] : 0.f;
        }
    }
#pragma unroll 8
    for (int k = 0; k < DD; ++k) {
        const float x0 = sX[r0 * DD + k];
        const float x1 = sX[(r0 + 1) * DD + k];
#pragma unroll
        for (int j = 0; j < 6; ++j) {
            const float w = sW[k * DD + c0 + j];
            a0[j] = fmaf(x0, w, a0[j]);
            a1[j] = fmaf(x1, w, a1[j]);
        }
    }
#pragma unroll
    for (int j = 0; j < 6; ++j) {
        sA[r0 * DD + c0 + j] = a0[j];
        sA[(r0 + 1) * DD + c0 + j] = a1[j];
    }
    __syncthreads();

    // ---- phase 2: o = Wb + a1 @ W1
    for (int i = tid; i < DD * DD / 4; i += 256)
        reinterpret_cast<float4*>(sW)[i] = reinterpret_cast<const float4*>(Ww)[i];
    if (tid < DD / 4)
        reinterpret_cast<float4*>(sB)[tid] = reinterpret_cast<const float4*>(Wb)[tid];
    __syncthreads();

    float o0[6], o1[6];
#pragma unroll
    for (int j = 0; j < 6; ++j) { o0[j] = sB[c0 + j]; o1[j] = sB[c0 + j]; }
#pragma unroll 8
    for (int k = 0; k < DD; ++k) {
        const float x0 = sA[r0 * DD + k];
        const float x1 = sA[(r0 + 1) * DD + k];
#pragma unroll
        for (int j = 0; j < 6; ++j) {
            const float w = sW[k * DD + c0 + j];
            o0[j] = fmaf(x0, w, o0[j]);
            o1[j] = fmaf(x1, w, o1[j]);
        }
    }
    __syncthreads();

    // ---- phase 3: o += V_in @ W2 ; out = relu(o)
    for (int i = tid; i < DD * DD / 4; i += 256)
        reinterpret_cast<float4*>(sW)[i] =
            reinterpret_cast<const float4*>(Ww + (size_t)DD * DD)[i];
    for (int i = tid; i < nr * DD / 4; i += 256)
        reinterpret_cast<float4*>(sX)[i] =
            reinterpret_cast<const float4*>(Vin + (size_t)row0 * DD)[i];
    __syncthreads();

#pragma unroll 8
    for (int k = 0; k < DD; ++k) {
        const float x0 = sX[r0 * DD + k];
        const float x1 = sX[(r0 + 1) * DD + k];
#pragma unroll
        for (int j = 0; j < 6; ++j) {
            const float w = sW[k * DD + c0 + j];
            o0[j] = fmaf(x0, w, o0[j]);
            o1[j] = fmaf(x1, w, o1[j]);
        }
    }

    if (rowA < NN) {
#pragma unroll
        for (int j = 0; j < 6; ++j)
            out[(size_t)rowA * DD + c0 + j] = fmaxf(o0[j], 0.f);
    }
    if (rowB < NN) {
#pragma unroll
        for (int j = 0; j < 6; ++j)
            out[(size_t)rowB * DD + c0 + j] = fmaxf(o1[j], 0.f);
    }
}

// ---------------------------------------------------------------------------
extern "C" void kernel_launch(void* const* d_in, const int* in_sizes, int n_in,
                              void* d_out, int out_size, void* d_ws, size_t ws_size,
                              hipStream_t stream)
{
    const float* V   = (const float*)d_in[0];
    const float* Vin = (const float*)d_in[1];
    const float* E   = (const float*)d_in[2];
    const float* ea  = (const float*)d_in[3];
    const int*   src = (const int*)d_in[4];
    const int*   dst = (const int*)d_in[5];
    const float* Aw  = (const float*)d_in[6];
    const float* Ab  = (const float*)d_in[7];
    const float* Mw  = (const float*)d_in[8];
    const float* Mb  = (const float*)d_in[9];
    const float* Ww  = (const float*)d_in[10];
    const float* Wb  = (const float*)d_in[11];
    float* out = (float*)d_out;

    float* Vp   = (float*)d_ws;
    float* aggV = Vp + (size_t)NN * DD;
    float* G    = aggV + (size_t)NN * DD;
    float* ssum = G + (size_t)NN * DD;

    // zero the accumulators (aggV, G, ssum are contiguous)
    hipMemsetAsync(aggV, 0, ((size_t)NN * DD * 2 + NN) * sizeof(float), stream);

    k_vp<<<(NN + 31) / 32, 256, 0, stream>>>(V, Aw, Ab, Vp);

    const int nthreads = NE * 24;
    k_edge<<<(nthreads + 255) / 256, 256, 0, stream>>>(Vp, E, ea, src, dst,
                                                       aggV, G, ssum);

    k_out<<<(NN + 31) / 32, 256, 0, stream>>>(aggV, G, ssum, Vin,
                                              Mw, Mb, Ww, Wb, out);
}

// Round 2
// 432.325 us; speedup vs baseline: 5.0095x; 5.0095x over previous
//
#include <hip/hip_runtime.h>
#include <hip/hip_bf16.h>

#define NN 50000
#define NE 800000
#define DD 96

// ---------------------------------------------------------------------------
// Kernel 1: Vp = relu(leaky_relu(V) @ A_w + A_b)
// ---------------------------------------------------------------------------
__global__ __launch_bounds__(256) void k_vp(
    const float* __restrict__ V, const float* __restrict__ Aw,
    const float* __restrict__ Ab, float* __restrict__ Vp)
{
    __shared__ float sW[DD * DD];
    __shared__ float sV[32 * DD];
    __shared__ float sB[DD];

    const int tid = threadIdx.x;

    for (int i = tid; i < DD * DD / 4; i += 256)
        reinterpret_cast<float4*>(sW)[i] = reinterpret_cast<const float4*>(Aw)[i];
    if (tid < DD / 4)
        reinterpret_cast<float4*>(sB)[tid] = reinterpret_cast<const float4*>(Ab)[tid];

    const int row0 = blockIdx.x * 32;
    const int nr = min(32, NN - row0);
    for (int i = tid; i < nr * DD / 4; i += 256) {
        float4 v = reinterpret_cast<const float4*>(V + (size_t)row0 * DD)[i];
        v.x = v.x > 0.f ? v.x : 0.2f * v.x;
        v.y = v.y > 0.f ? v.y : 0.2f * v.y;
        v.z = v.z > 0.f ? v.z : 0.2f * v.z;
        v.w = v.w > 0.f ? v.w : 0.2f * v.w;
        reinterpret_cast<float4*>(sV)[i] = v;
    }
    __syncthreads();

    const int cg = tid & 15;
    const int rg = tid >> 4;
    const int c0 = cg * 6;
    const int r0 = rg * 2;

    float acc0[6], acc1[6];
#pragma unroll
    for (int j = 0; j < 6; ++j) { acc0[j] = sB[c0 + j]; acc1[j] = sB[c0 + j]; }

#pragma unroll 8
    for (int k = 0; k < DD; ++k) {
        const float v0 = sV[r0 * DD + k];
        const float v1 = sV[(r0 + 1) * DD + k];
#pragma unroll
        for (int j = 0; j < 6; ++j) {
            const float w = sW[k * DD + c0 + j];
            acc0[j] = fmaf(v0, w, acc0[j]);
            acc1[j] = fmaf(v1, w, acc1[j]);
        }
    }

    const int rowA = row0 + r0;
    if (rowA < NN) {
#pragma unroll
        for (int j = 0; j < 6; ++j)
            Vp[(size_t)rowA * DD + c0 + j] = fmaxf(acc0[j], 0.f);
    }
    if (rowA + 1 < NN) {
#pragma unroll
        for (int j = 0; j < 6; ++j)
            Vp[(size_t)(rowA + 1) * DD + c0 + j] = fmaxf(acc1[j], 0.f);
    }
}

// ---------------------------------------------------------------------------
// Kernel 2a: histogram of dst
// ---------------------------------------------------------------------------
__global__ __launch_bounds__(256) void k_hist(
    const int* __restrict__ dst, int* __restrict__ cnt)
{
    const int e = blockIdx.x * 256 + threadIdx.x;
    if (e < NE) atomicAdd(&cnt[dst[e]], 1);
}

// ---------------------------------------------------------------------------
// Kernel 2b: exclusive scan of cnt -> off (NN+1) and cursor (copy of off)
// single block, 1024 threads, Hillis-Steele per 1024-chunk with carry
// ---------------------------------------------------------------------------
__global__ __launch_bounds__(1024) void k_scan(
    const int* __restrict__ cnt, int* __restrict__ off, int* __restrict__ cursor)
{
    __shared__ int buf[1024];
    __shared__ int carry;
    const int tid = threadIdx.x;
    if (tid == 0) carry = 0;
    __syncthreads();

    for (int base = 0; base < NN; base += 1024) {
        const int i = base + tid;
        const int v = (i < NN) ? cnt[i] : 0;
        buf[tid] = v;
        __syncthreads();
        for (int s = 1; s < 1024; s <<= 1) {
            int t = (tid >= s) ? buf[tid - s] : 0;
            __syncthreads();
            buf[tid] += t;
            __syncthreads();
        }
        const int incl = buf[tid];
        const int excl = incl - v;
        const int cb = carry;
        if (i < NN) { off[i] = cb + excl; cursor[i] = cb + excl; }
        const int ctot = buf[1023];
        __syncthreads();
        if (tid == 0) carry = cb + ctot;
        __syncthreads();
    }
    if (tid == 0) off[NN] = carry;
}

// ---------------------------------------------------------------------------
// Kernel 2c: scatter edges into dst-sorted order
// ---------------------------------------------------------------------------
__global__ __launch_bounds__(256) void k_scatter(
    const int* __restrict__ src, const int* __restrict__ dst,
    const float* __restrict__ ea, int* __restrict__ cursor,
    int* __restrict__ srcs, int* __restrict__ eid, float* __restrict__ wsrt)
{
    const int e = blockIdx.x * 256 + threadIdx.x;
    if (e >= NE) return;
    const int d = dst[e];
    const int pos = atomicAdd(&cursor[d], 1);
    srcs[pos] = src[e];
    eid[pos]  = e;
    wsrt[pos] = ea[(size_t)e * 4 + 1];
}

// ---------------------------------------------------------------------------
// Kernel 2d: per-node aggregation, no atomics.
// 24 threads per node (float4 over 96 cols), 192-thread blocks = 8 nodes.
//   aggV[n] = sum w*Vp[src], G[n] = sum w*E[e], ssum[n] = sum w
// ---------------------------------------------------------------------------
__global__ __launch_bounds__(192) void k_agg(
    const float* __restrict__ Vp, const float* __restrict__ E,
    const int* __restrict__ off, const int* __restrict__ srcs,
    const int* __restrict__ eid, const float* __restrict__ wsrt,
    float* __restrict__ aggV, float* __restrict__ G, float* __restrict__ ssum)
{
    const int t = threadIdx.x;
    const int node = blockIdx.x * 8 + t / 24;
    const int c4 = t % 24;
    if (node >= NN) return;

    const int beg = off[node];
    const int end = off[node + 1];

    float4 av = {0.f, 0.f, 0.f, 0.f};
    float4 ag = {0.f, 0.f, 0.f, 0.f};
    float wsum = 0.f;

    for (int i = beg; i < end; ++i) {
        const int e = eid[i];
        const int s = srcs[i];
        const float w = wsrt[i];
        const float4 Ev = reinterpret_cast<const float4*>(E + (size_t)e * DD)[c4];
        const float4 Vv = reinterpret_cast<const float4*>(Vp + (size_t)s * DD)[c4];
        av.x = fmaf(w, Vv.x, av.x);
        av.y = fmaf(w, Vv.y, av.y);
        av.z = fmaf(w, Vv.z, av.z);
        av.w = fmaf(w, Vv.w, av.w);
        ag.x = fmaf(w, Ev.x, ag.x);
        ag.y = fmaf(w, Ev.y, ag.y);
        ag.z = fmaf(w, Ev.z, ag.z);
        ag.w = fmaf(w, Ev.w, ag.w);
        wsum += w;
    }

    reinterpret_cast<float4*>(aggV + (size_t)node * DD)[c4] = av;
    reinterpret_cast<float4*>(G + (size_t)node * DD)[c4] = ag;
    if (c4 == 0) ssum[node] = wsum;
}

// ---------------------------------------------------------------------------
// Kernel 3: fused finalize (unchanged from R1).
//   a1  = aggV + G @ M_w + ssum * M_b
//   out = relu(a1 @ W1 + V_in @ W2 + W_b)
// ---------------------------------------------------------------------------
__global__ __launch_bounds__(256) void k_out(
    const float* __restrict__ aggV, const float* __restrict__ G,
    const float* __restrict__ ssum, const float* __restrict__ Vin,
    const float* __restrict__ Mw, const float* __restrict__ Mb,
    const float* __restrict__ Ww, const float* __restrict__ Wb,
    float* __restrict__ out)
{
    __shared__ float sW[DD * DD];
    __shared__ float sX[32 * DD];
    __shared__ float sA[32 * DD];
    __shared__ float sB[DD];

    const int tid = threadIdx.x;
    const int row0 = blockIdx.x * 32;
    const int nr = min(32, NN - row0);
    const int cg = tid & 15;
    const int rg = tid >> 4;
    const int c0 = cg * 6;
    const int r0 = rg * 2;
    const int rowA = row0 + r0;
    const int rowB = rowA + 1;

    // ---- phase 1: a1 = aggV + G @ Mw + ssum * Mb
    for (int i = tid; i < DD * DD / 4; i += 256)
        reinterpret_cast<float4*>(sW)[i] = reinterpret_cast<const float4*>(Mw)[i];
    for (int i = tid; i < nr * DD / 4; i += 256)
        reinterpret_cast<float4*>(sX)[i] =
            reinterpret_cast<const float4*>(G + (size_t)row0 * DD)[i];
    if (tid < DD / 4)
        reinterpret_cast<float4*>(sB)[tid] = reinterpret_cast<const float4*>(Mb)[tid];
    __syncthreads();

    float a0[6], a1[6];
    {
        const float s0 = (rowA < NN) ? ssum[rowA] : 0.f;
        const float s1 = (rowB < NN) ? ssum[rowB] : 0.f;
#pragma unroll
        for (int j = 0; j < 6; ++j) {
            a0[j] = (rowA < NN) ? aggV[(size_t)rowA * DD + c0 + j] + s0 * sB[c0 + j] : 0.f;
            a1[j] = (rowB < NN) ? aggV[(size_t)rowB * DD + c0 + j] + s1 * sB[c0 + j] : 0.f;
        }
    }
#pragma unroll 8
    for (int k = 0; k < DD; ++k) {
        const float x0 = sX[r0 * DD + k];
        const float x1 = sX[(r0 + 1) * DD + k];
#pragma unroll
        for (int j = 0; j < 6; ++j) {
            const float w = sW[k * DD + c0 + j];
            a0[j] = fmaf(x0, w, a0[j]);
            a1[j] = fmaf(x1, w, a1[j]);
        }
    }
#pragma unroll
    for (int j = 0; j < 6; ++j) {
        sA[r0 * DD + c0 + j] = a0[j];
        sA[(r0 + 1) * DD + c0 + j] = a1[j];
    }
    __syncthreads();

    // ---- phase 2: o = Wb + a1 @ W1
    for (int i = tid; i < DD * DD / 4; i += 256)
        reinterpret_cast<float4*>(sW)[i] = reinterpret_cast<const float4*>(Ww)[i];
    if (tid < DD / 4)
        reinterpret_cast<float4*>(sB)[tid] = reinterpret_cast<const float4*>(Wb)[tid];
    __syncthreads();

    float o0[6], o1[6];
#pragma unroll
    for (int j = 0; j < 6; ++j) { o0[j] = sB[c0 + j]; o1[j] = sB[c0 + j]; }
#pragma unroll 8
    for (int k = 0; k < DD; ++k) {
        const float x0 = sA[r0 * DD + k];
        const float x1 = sA[(r0 + 1) * DD + k];
#pragma unroll
        for (int j = 0; j < 6; ++j) {
            const float w = sW[k * DD + c0 + j];
            o0[j] = fmaf(x0, w, o0[j]);
            o1[j] = fmaf(x1, w, o1[j]);
        }
    }
    __syncthreads();

    // ---- phase 3: o += V_in @ W2 ; out = relu(o)
    for (int i = tid; i < DD * DD / 4; i += 256)
        reinterpret_cast<float4*>(sW)[i] =
            reinterpret_cast<const float4*>(Ww + (size_t)DD * DD)[i];
    for (int i = tid; i < nr * DD / 4; i += 256)
        reinterpret_cast<float4*>(sX)[i] =
            reinterpret_cast<const float4*>(Vin + (size_t)row0 * DD)[i];
    __syncthreads();

#pragma unroll 8
    for (int k = 0; k < DD; ++k) {
        const float x0 = sX[r0 * DD + k];
        const float x1 = sX[(r0 + 1) * DD + k];
#pragma unroll
        for (int j = 0; j < 6; ++j) {
            const float w = sW[k * DD + c0 + j];
            o0[j] = fmaf(x0, w, o0[j]);
            o1[j] = fmaf(x1, w, o1[j]);
        }
    }

    if (rowA < NN) {
#pragma unroll
        for (int j = 0; j < 6; ++j)
            out[(size_t)rowA * DD + c0 + j] = fmaxf(o0[j], 0.f);
    }
    if (rowB < NN) {
#pragma unroll
        for (int j = 0; j < 6; ++j)
            out[(size_t)rowB * DD + c0 + j] = fmaxf(o1[j], 0.f);
    }
}

// ---------------------------------------------------------------------------
extern "C" void kernel_launch(void* const* d_in, const int* in_sizes, int n_in,
                              void* d_out, int out_size, void* d_ws, size_t ws_size,
                              hipStream_t stream)
{
    const float* V   = (const float*)d_in[0];
    const float* Vin = (const float*)d_in[1];
    const float* E   = (const float*)d_in[2];
    const float* ea  = (const float*)d_in[3];
    const int*   src = (const int*)d_in[4];
    const int*   dst = (const int*)d_in[5];
    const float* Aw  = (const float*)d_in[6];
    const float* Ab  = (const float*)d_in[7];
    const float* Mw  = (const float*)d_in[8];
    const float* Mb  = (const float*)d_in[9];
    const float* Ww  = (const float*)d_in[10];
    const float* Wb  = (const float*)d_in[11];
    float* out = (float*)d_out;

    // workspace layout (all 4-byte elems; float4-accessed arrays 16B-aligned)
    float* Vp   = (float*)d_ws;                    // NN*DD
    float* aggV = Vp + (size_t)NN * DD;            // NN*DD
    float* G    = aggV + (size_t)NN * DD;          // NN*DD
    float* ssum = G + (size_t)NN * DD;             // NN
    int*   cnt    = (int*)(ssum + NN);             // NN
    int*   off    = cnt + NN;                      // NN+1
    int*   cursor = off + NN + 1;                  // NN
    int*   srcs   = cursor + NN;                   // NE
    int*   eid    = srcs + NE;                     // NE
    float* wsrt   = (float*)(eid + NE);            // NE

    hipMemsetAsync(cnt, 0, NN * sizeof(int), stream);

    k_vp<<<(NN + 31) / 32, 256, 0, stream>>>(V, Aw, Ab, Vp);

    k_hist<<<(NE + 255) / 256, 256, 0, stream>>>(dst, cnt);
    k_scan<<<1, 1024, 0, stream>>>(cnt, off, cursor);
    k_scatter<<<(NE + 255) / 256, 256, 0, stream>>>(src, dst, ea, cursor,
                                                    srcs, eid, wsrt);
    k_agg<<<(NN + 7) / 8, 192, 0, stream>>>(Vp, E, off, srcs, eid, wsrt,
                                            aggV, G, ssum);

    k_out<<<(NN + 31) / 32, 256, 0, stream>>>(aggV, G, ssum, Vin,
                                              Mw, Mb, Ww, Wb, out);
}